// Round 11
// baseline (288.147 us; speedup 1.0000x reference)
//
#include <hip/hip_runtime.h>
#include <hip/hip_bf16.h>
#include <stdint.h>

// FP8QDQLinear: out[m,o] = 4 * (q_in @ q_w^T) + bias, q_* exact e4m3 values.
// R11: 256^2 tile, 16 waves (1024 thr, 4x4), wave tile 64x64 -> 4 waves/SIMD
// so LDS-read drain overlaps MFMA via wave skew (R5/R9 at 2 waves/SIMD were
// serial: drain-then-MFMA each phase). R9's verified X/Y ledger kept:
//   X(k): READ_A_ALL + READ_B2(0) | BAR | 8 MFMA
//   Y(k): READ_B2(1) | VMW(0: drains the 4 tiles staged at Y(k-1), ~1.5
//         phases aged) | BAR | stage B(k+2),A(k+2) (post-BAR, into current-
//         parity buffers) | 8 MFMA
// Every stage lands >=1 barrier after the last ds_read of its target region;
// loads in flight across >=1 full phase; never drains just-issued loads.
// MX-fp8 16x16x128, unit E8M0 scales = exact e4m3 math. LDS column-chunk
// layout (slot = col16*256 + row), conflict-free (verified 0 since R3).

typedef __attribute__((ext_vector_type(4))) float f32x4;
typedef __attribute__((ext_vector_type(2))) int i32x2;
typedef __attribute__((ext_vector_type(4))) int i32x4;
typedef __attribute__((ext_vector_type(8))) int i32x8;

#define FP8_MAX 448.0f
#define UNIT_SCALE 0x7F7F7F7F  // E8M0 127 = 2^0 in every byte

// ---------------- quantization pass: f32 -> e4m3fn bytes ----------------
__global__ void quant_fp8_kernel(const float* __restrict__ x,
                                 uint32_t* __restrict__ q,
                                 float mul, int n8) {
    int i = blockIdx.x * blockDim.x + threadIdx.x;
    if (i >= n8) return;
    const float4* xv = (const float4*)x;
    float4 v0 = xv[2 * i];
    float4 v1 = xv[2 * i + 1];
    float a[8] = {v0.x, v0.y, v0.z, v0.w, v1.x, v1.y, v1.z, v1.w};
#pragma unroll
    for (int j = 0; j < 8; ++j) {
        float t = a[j] * mul;
        t = fminf(fmaxf(t, -FP8_MAX), FP8_MAX);
        a[j] = t;
    }
    int lo = 0, hi = 0;
    lo = __builtin_amdgcn_cvt_pk_fp8_f32(a[0], a[1], lo, false);
    lo = __builtin_amdgcn_cvt_pk_fp8_f32(a[2], a[3], lo, true);
    hi = __builtin_amdgcn_cvt_pk_fp8_f32(a[4], a[5], hi, false);
    hi = __builtin_amdgcn_cvt_pk_fp8_f32(a[6], a[7], hi, true);
    i32x2 out;
    out.x = lo;
    out.y = hi;
    ((i32x2*)q)[i] = out;
}

// ---------------- MX-fp8 GEMM: C = 4*(A_q @ W_q^T) + bias ----------------
#define KTILES 32  // K / 128

__device__ static inline void gload_lds16(const void* g, void* l) {
    __builtin_amdgcn_global_load_lds(
        (const __attribute__((address_space(1))) void*)g,
        (__attribute__((address_space(3))) void*)l, 16, 0, 0);
}

// stage a full 32 KB operand K-tile: 2 calls x (1024 thr x 16B)
// call c covers col16 = c*4 + (t>>8), row = t&255; dest chunk = c*1024 + t
#define STAGE_FULL(GSRC, KB, LBASE)                                       \
    gload_lds16((GSRC) + (KB),      (LBASE) + t * 16);                    \
    gload_lds16((GSRC) + (KB) + 64, (LBASE) + 16384 + t * 16);

#define READ_A_ALL(LBASE)                                                  \
    _Pragma("unroll") for (int m = 0; m < 4; ++m) {                        \
        i32x4 lo = *(const i32x4*)((LBASE) + aoff + m * 256);                     \
        i32x4 hi = *(const i32x4*)((LBASE) + aoff + m * 256 + 4096);              \
        areg[m] = (i32x8){lo[0], lo[1], lo[2], lo[3], hi[0], hi[1], hi[2], hi[3]};\
    }

#define READ_B2(LBASE, NH)                                                 \
    _Pragma("unroll") for (int n = 0; n < 2; ++n) {                        \
        i32x4 lo = *(const i32x4*)((LBASE) + boff + (NH) * 512 + n * 256);        \
        i32x4 hi = *(const i32x4*)((LBASE) + boff + (NH) * 512 + n * 256 + 4096); \
        breg[n] = (i32x8){lo[0], lo[1], lo[2], lo[3], hi[0], hi[1], hi[2], hi[3]};\
    }

#define MFMA8(NH)                                                          \
    __builtin_amdgcn_s_setprio(1);                                         \
    _Pragma("unroll") for (int m = 0; m < 4; ++m)                          \
        _Pragma("unroll") for (int n = 0; n < 2; ++n)                      \
            acc[m][(NH) * 2 + n] =                                         \
                __builtin_amdgcn_mfma_scale_f32_16x16x128_f8f6f4(          \
                    areg[m], breg[n], acc[m][(NH) * 2 + n],                \
                    0, 0, 0, UNIT_SCALE, 0, UNIT_SCALE);                   \
    __builtin_amdgcn_s_setprio(0);

#define BAR() __builtin_amdgcn_s_barrier()
#define VMW(N) asm volatile("s_waitcnt vmcnt(" #N ")" ::: "memory")

__global__ __launch_bounds__(1024) void fp8_gemm_bias_kernel(
        const uint8_t* __restrict__ Aq, const uint8_t* __restrict__ Wq,
        const float* __restrict__ bias, float* __restrict__ C,
        int M, int N, int K) {
    // layout: [A0 | B0 | A1 | B1], each 32 KiB; computed offsets only
    // (LDS pointer arrays trip an unsupported addrspacecast initializer).
    __shared__ __align__(16) uint8_t lds[131072];

    const int t = threadIdx.x;
    const int lane = t & 63;
    const int w = t >> 6;       // wave 0..15
    const int wrow = w >> 2;    // wave row 0..3  (64 rows each)
    const int wcol = w & 3;     // wave col 0..3  (64 cols each)
    const int lr = lane & 15;
    const int lk = lane >> 4;   // K-group (32 bytes)

    // XCD-aware swizzle: 256 blocks, 8 XCDs, 32 per XCD
    const int bid = blockIdx.x;
    const int swz = (bid & 7) * 32 + (bid >> 3);
    const int bm = swz >> 4;
    const int bn = swz & 15;

    const uint8_t* Abase = Aq + (size_t)(bm * 256) * K;
    const uint8_t* Bbase = Wq + (size_t)(bn * 256) * K;

    // staging source: row = t&255, base col16 = t>>8 (call c adds 4)
    const int srow = t & 255;
    const int scol = (t >> 8) * 16;
    const uint8_t* gA = Abase + (size_t)srow * K + scol;
    const uint8_t* gB = Bbase + (size_t)srow * K + scol;

    // fragment read bases: row = wrow*64 + m*16 + lr, col16 pair (2lk, 2lk+1)
    const int aoff = lk * 8192 + wrow * 1024 + lr * 16;
    const int boff = lk * 8192 + wcol * 1024 + lr * 16;

    f32x4 acc[4][4];
#pragma unroll
    for (int mi = 0; mi < 4; ++mi)
#pragma unroll
        for (int ni = 0; ni < 4; ++ni)
            acc[mi][ni] = (f32x4){0.f, 0.f, 0.f, 0.f};

    i32x8 areg[4], breg[2];

    // ---- prologue: A0,B0 -> buf0; B1,A1 -> buf1 (B1,A1 stay in flight) ----
    STAGE_FULL(gA, 0, lds)                  // A(0) -> sA0
    STAGE_FULL(gB, 0, lds + 32768)          // B(0) -> sB0
    STAGE_FULL(gB, 128, lds + 98304)        // B(1) -> sB1
    STAGE_FULL(gA, 128, lds + 65536)        // A(1) -> sA1
    VMW(4);   // 8 outstanding -> drain oldest 4 = A(0)+B(0); B(1),A(1) fly
    BAR();

    for (int k = 0; k < KTILES; ++k) {
        const int co = (k & 1) << 16;       // current buffer byte offset
        uint8_t* const sAc = lds + co;
        uint8_t* const sBc = lds + 32768 + co;
        const int kbN = ((k + 2) & 31) * 128;  // tile k+2 (same parity -> cur)

        // ---- phase X: all A frags + B frags 0,1 ----
        READ_A_ALL(sAc)
        READ_B2(sBc, 0)
        BAR();
        MFMA8(0)

        // ---- phase Y: B frags 2,3; drain aged stages; stage k+2 post-BAR ----
        READ_B2(sBc, 1)
        VMW(0);   // drains B(k+1)+A(k+1) (issued at Y(k-1), ~1.5 phases aged)
        BAR();
        STAGE_FULL(gB, kbN, sBc)
        STAGE_FULL(gA, kbN, sAc)
        MFMA8(1)
    }

    VMW(0);  // drain wrap-tail stages before epilogue

    // ---- epilogue: C/D layout col=lane&15, row=(lane>>4)*4+j ----
    const int crow0 = bm * 256 + wrow * 64 + lk * 4;
    const int ccol0 = bn * 256 + wcol * 64 + lr;
#pragma unroll
    for (int ni = 0; ni < 4; ++ni) {
        const int col = ccol0 + ni * 16;
        const float bv = bias[col];
#pragma unroll
        for (int mi = 0; mi < 4; ++mi) {
            const int row = crow0 + mi * 16;
#pragma unroll
            for (int j = 0; j < 4; ++j) {
                C[(size_t)(row + j) * N + col] = acc[mi][ni][j] * 4.0f + bv;
            }
        }
    }
}

extern "C" void kernel_launch(void* const* d_in, const int* in_sizes, int n_in,
                              void* d_out, int out_size, void* d_ws, size_t ws_size,
                              hipStream_t stream) {
    const int M = 4096, N = 4096, K = 4096;
    const float* input  = (const float*)d_in[0];   // [M][K] f32
    const float* weight = (const float*)d_in[1];   // [N][K] f32 (e4m3-grid values)
    const float* bias   = (const float*)d_in[2];   // [N] f32
    float* out = (float*)d_out;                    // [M][N] f32

    uint8_t* Aq = (uint8_t*)d_ws;                        // 16 MiB
    uint8_t* Wq = (uint8_t*)d_ws + (size_t)M * K;        // 16 MiB

    {
        int n8 = (M * K) / 8;
        int blocks = (n8 + 255) / 256;
        quant_fp8_kernel<<<blocks, 256, 0, stream>>>(input, (uint32_t*)Aq, 0.5f, n8);
        quant_fp8_kernel<<<blocks, 256, 0, stream>>>(weight, (uint32_t*)Wq, 1.0f, n8);
    }

    dim3 grid(256);  // (M/256) x (N/256), XCD-swizzled in-kernel
    fp8_gemm_bias_kernel<<<grid, 1024, 0, stream>>>(Aq, Wq, bias, out, M, N, K);
}

// Round 12
// 181.412 us; speedup vs baseline: 1.5884x; 1.5884x over previous
//
#include <hip/hip_runtime.h>
#include <hip/hip_bf16.h>
#include <stdint.h>

// FP8QDQLinear: out[m,o] = 4 * (q_in @ q_w^T) + bias, q_* exact e4m3 values.
// R12: register-pipelined phases on the R9 512-thr frame (R11's 1024-thr
// spilled acc -> reverted). Each phase reads the NEXT cluster's operands
// while current cluster's MFMAs run off registers (m201's overhead model):
//   X(k): read A_mh1(k)->aY | MFMA(aX,b[k],mh0) | VMW(0) pre-BAR | BAR
//   Y(k): read A_mh0(k+1)->aX, B(k+1)->b[k+1&1] | stage tiles k+2 | MFMA(aY,
//         b[k],mh1) | BAR
// VMW(0) at X-end drains the 8 stage-calls issued mid-Y(k-1) (>=1 phase aged,
// never just-issued; pre-barrier => cross-wave visible, R5-proven pattern).
// Overwrite audit: stage A(k+2) at Y(k) — last read of that region is
// A_mh1(k) at X(k), 1 barrier earlier; stage B(k+2) — last read B(k) at
// Y(k-1), 2 barriers earlier. B double-banked (bE/bO) so Y's B-read never
// clobbers the cluster's live operands. MX-fp8 16x16x128, unit E8M0 scales =
// exact e4m3 math. LDS column-chunk layout (slot=col16*256+row), 0 conflicts.

typedef __attribute__((ext_vector_type(4))) float f32x4;
typedef __attribute__((ext_vector_type(2))) int i32x2;
typedef __attribute__((ext_vector_type(4))) int i32x4;
typedef __attribute__((ext_vector_type(8))) int i32x8;

#define FP8_MAX 448.0f
#define UNIT_SCALE 0x7F7F7F7F  // E8M0 127 = 2^0 in every byte

// ---------------- quantization pass: f32 -> e4m3fn bytes ----------------
__global__ void quant_fp8_kernel(const float* __restrict__ x,
                                 uint32_t* __restrict__ q,
                                 float mul, int n8) {
    int i = blockIdx.x * blockDim.x + threadIdx.x;
    if (i >= n8) return;
    const float4* xv = (const float4*)x;
    float4 v0 = xv[2 * i];
    float4 v1 = xv[2 * i + 1];
    float a[8] = {v0.x, v0.y, v0.z, v0.w, v1.x, v1.y, v1.z, v1.w};
#pragma unroll
    for (int j = 0; j < 8; ++j) {
        float t = a[j] * mul;
        t = fminf(fmaxf(t, -FP8_MAX), FP8_MAX);
        a[j] = t;
    }
    int lo = 0, hi = 0;
    lo = __builtin_amdgcn_cvt_pk_fp8_f32(a[0], a[1], lo, false);
    lo = __builtin_amdgcn_cvt_pk_fp8_f32(a[2], a[3], lo, true);
    hi = __builtin_amdgcn_cvt_pk_fp8_f32(a[4], a[5], hi, false);
    hi = __builtin_amdgcn_cvt_pk_fp8_f32(a[6], a[7], hi, true);
    i32x2 out;
    out.x = lo;
    out.y = hi;
    ((i32x2*)q)[i] = out;
}

// ---------------- MX-fp8 GEMM: C = 4*(A_q @ W_q^T) + bias ----------------
#define KTILES 32  // K / 128

__device__ static inline void gload_lds16(const void* g, void* l) {
    __builtin_amdgcn_global_load_lds(
        (const __attribute__((address_space(1))) void*)g,
        (__attribute__((address_space(3))) void*)l, 16, 0, 0);
}

// stage a full 32 KB operand K-tile: 4 calls x (512 thr x 16B)
#define STAGE_OP(GSRC, KB, LBASE)                                          \
    gload_lds16((GSRC) + (KB),      (LBASE) + t * 16);                     \
    gload_lds16((GSRC) + (KB) + 32, (LBASE) + 8192  + t * 16);             \
    gload_lds16((GSRC) + (KB) + 64, (LBASE) + 16384 + t * 16);             \
    gload_lds16((GSRC) + (KB) + 96, (LBASE) + 24576 + t * 16);

#define READ_A(LBASE, MH, DST)                                             \
    _Pragma("unroll") for (int m = 0; m < 4; ++m) {                        \
        i32x4 lo = *(const i32x4*)((LBASE) + aoff + (MH) * 1024 + m * 256);       \
        i32x4 hi = *(const i32x4*)((LBASE) + aoff + (MH) * 1024 + m * 256 + 4096);\
        DST[m] = (i32x8){lo[0], lo[1], lo[2], lo[3], hi[0], hi[1], hi[2], hi[3]}; \
    }

#define READ_B(LBASE, DST)                                                 \
    _Pragma("unroll") for (int n = 0; n < 4; ++n) {                        \
        i32x4 lo = *(const i32x4*)((LBASE) + boff + n * 256);                     \
        i32x4 hi = *(const i32x4*)((LBASE) + boff + n * 256 + 4096);              \
        DST[n] = (i32x8){lo[0], lo[1], lo[2], lo[3], hi[0], hi[1], hi[2], hi[3]}; \
    }

#define MFMA16(AR, BR, MH)                                                 \
    __builtin_amdgcn_s_setprio(1);                                         \
    _Pragma("unroll") for (int m = 0; m < 4; ++m)                          \
        _Pragma("unroll") for (int n = 0; n < 4; ++n)                      \
            acc[(MH) * 4 + m][n] =                                         \
                __builtin_amdgcn_mfma_scale_f32_16x16x128_f8f6f4(          \
                    AR[m], BR[n], acc[(MH) * 4 + m][n],                    \
                    0, 0, 0, UNIT_SCALE, 0, UNIT_SCALE);                   \
    __builtin_amdgcn_s_setprio(0);

#define BAR() __builtin_amdgcn_s_barrier()
#define VMW(N) asm volatile("s_waitcnt vmcnt(" #N ")" ::: "memory")

__global__ __launch_bounds__(512, 2) void fp8_gemm_bias_kernel(
        const uint8_t* __restrict__ Aq, const uint8_t* __restrict__ Wq,
        const float* __restrict__ bias, float* __restrict__ C,
        int M, int N, int K) {
    // layout: [A0 | B0 | A1 | B1], each 32 KiB; computed offsets only.
    __shared__ __align__(16) uint8_t lds[131072];
    uint8_t* const LA0 = lds;
    uint8_t* const LB0 = lds + 32768;
    uint8_t* const LA1 = lds + 65536;
    uint8_t* const LB1 = lds + 98304;

    const int t = threadIdx.x;
    const int lane = t & 63;
    const int w = t >> 6;       // wave 0..7
    const int wr = w >> 2;      // wave row 0..1  (128 rows each)
    const int wc = w & 3;       // wave col 0..3  (64 cols each)
    const int lr = lane & 15;
    const int lk = lane >> 4;   // K-group (32 bytes)

    // XCD-aware swizzle: 256 blocks, 8 XCDs, 32 per XCD
    const int bid = blockIdx.x;
    const int swz = (bid & 7) * 32 + (bid >> 3);
    const int bm = swz >> 4;
    const int bn = swz & 15;

    const uint8_t* Abase = Aq + (size_t)(bm * 256) * K;
    const uint8_t* Bbase = Wq + (size_t)(bn * 256) * K;

    // staging source: call c: row = t&255, col16 = 2c + (t>>8)
    const int srow = t & 255;
    const int scol = (t >> 8) * 16;
    const uint8_t* gA = Abase + (size_t)srow * K + scol;
    const uint8_t* gB = Bbase + (size_t)srow * K + scol;

    // fragment read bases: A row = wr*128 + mh*64 + m*16 + lr, cols (2lk,2lk+1)
    const int aoff = lk * 8192 + wr * 2048 + lr * 16;
    const int boff = lk * 8192 + wc * 1024 + lr * 16;

    f32x4 acc[8][4];
#pragma unroll
    for (int mi = 0; mi < 8; ++mi)
#pragma unroll
        for (int ni = 0; ni < 4; ++ni)
            acc[mi][ni] = (f32x4){0.f, 0.f, 0.f, 0.f};

    i32x8 aX[4], aY[4], bE[4], bO[4];

    // ---- prologue ----
    STAGE_OP(gA, 0, LA0)            // A(0)
    STAGE_OP(gB, 0, LB0)            // B(0)
    VMW(0);                          // pre-barrier drain -> cross-wave visible
    BAR();
    READ_A(LA0, 0, aX)               // A_mh0(0)
    READ_B(LB0, bE)                  // B(0)
    STAGE_OP(gA, 128, LA1)           // A(1) — in flight across X(0)
    STAGE_OP(gB, 128, LB1)           // B(1)
    BAR();

    for (int kk = 0; kk < KTILES / 2; ++kk) {
        const int kb2 = ((2 * kk + 2) & 31) * 128;
        const int kb3 = ((2 * kk + 3) & 31) * 128;

        // ---- X(2kk): buf0, B bank E ----
        READ_A(LA0, 1, aY)           // operands for Y(2kk)
        MFMA16(aX, bE, 0)
        VMW(0);                      // drains A(2kk+1),B(2kk+1) stages (>=1 phase aged)
        BAR();
        // ---- Y(2kk) ----
        READ_A(LA1, 0, aX)           // A_mh0(2kk+1) for X(2kk+1)
        READ_B(LB1, bO)              // B(2kk+1)
        STAGE_OP(gA, kb2, LA0)       // tile 2kk+2 (A0 last read 1 barrier ago)
        STAGE_OP(gB, kb2, LB0)       // (B0 last read 2 barriers ago)
        MFMA16(aY, bE, 1)
        BAR();

        // ---- X(2kk+1): buf1, B bank O ----
        READ_A(LA1, 1, aY)
        MFMA16(aX, bO, 0)
        VMW(0);                      // drains tile-(2kk+2) stages
        BAR();
        // ---- Y(2kk+1) ----
        READ_A(LA0, 0, aX)           // A_mh0(2kk+2)
        READ_B(LB0, bE)              // B(2kk+2)
        STAGE_OP(gA, kb3, LA1)       // tile 2kk+3
        STAGE_OP(gB, kb3, LB1)
        MFMA16(aY, bO, 1)
        BAR();
    }

    VMW(0);  // drain wrap-tail stages before epilogue

    // ---- epilogue: C/D layout col=lane&15, row=(lane>>4)*4+j ----
    const int crow0 = bm * 256 + wr * 128 + lk * 4;
    const int ccol0 = bn * 256 + wc * 64 + lr;
#pragma unroll
    for (int ni = 0; ni < 4; ++ni) {
        const int col = ccol0 + ni * 16;
        const float bv = bias[col];
#pragma unroll
        for (int mi = 0; mi < 8; ++mi) {
            const int row = crow0 + mi * 16;
#pragma unroll
            for (int j = 0; j < 4; ++j) {
                C[(size_t)(row + j) * N + col] = acc[mi][ni][j] * 4.0f + bv;
            }
        }
    }
}

extern "C" void kernel_launch(void* const* d_in, const int* in_sizes, int n_in,
                              void* d_out, int out_size, void* d_ws, size_t ws_size,
                              hipStream_t stream) {
    const int M = 4096, N = 4096, K = 4096;
    const float* input  = (const float*)d_in[0];   // [M][K] f32
    const float* weight = (const float*)d_in[1];   // [N][K] f32 (e4m3-grid values)
    const float* bias   = (const float*)d_in[2];   // [N] f32
    float* out = (float*)d_out;                    // [M][N] f32

    uint8_t* Aq = (uint8_t*)d_ws;                        // 16 MiB
    uint8_t* Wq = (uint8_t*)d_ws + (size_t)M * K;        // 16 MiB

    {
        int n8 = (M * K) / 8;
        int blocks = (n8 + 255) / 256;
        quant_fp8_kernel<<<blocks, 256, 0, stream>>>(input, (uint32_t*)Aq, 0.5f, n8);
        quant_fp8_kernel<<<blocks, 256, 0, stream>>>(weight, (uint32_t*)Wq, 1.0f, n8);
    }

    dim3 grid(256);  // (M/256) x (N/256), XCD-swizzled in-kernel
    fp8_gemm_bias_kernel<<<grid, 512, 0, stream>>>(Aq, Wq, bias, out, M, N, K);
}

// Round 13
// 137.271 us; speedup vs baseline: 2.0991x; 1.3216x over previous
//
#include <hip/hip_runtime.h>
#include <hip/hip_bf16.h>
#include <stdint.h>

// FP8QDQLinear: out[m,o] = 4 * (q_in @ q_w^T) + bias, q_* exact e4m3 values.
// R13: register-pipelined phases, sized to FIT (R12 spilled: 4 operand banks
// + acc > 256 regs/wave). 3 banks: aX, aY, breg (96 VGPR) + acc in AGPR;
// amdgpu_waves_per_eu(2,2) pins the allocator at 2 waves/SIMD (256-reg cap)
// so it doesn't squeeze to 128 and spill (R11/R12 failure mode).
// Schedule (2 barriers/K-tile, R9's proven separations):
//   X(k): READ_B(k)->breg | READ_A(k,mh1)->aY | MFMA(aX,breg,mh0) | VMW(0)
//         [drains A(k+1),B(k+1) staged at Y(k-1), ~1.5 phases aged] | BAR
//   Y(k): READ_A(k+1,mh0)->aX | stage A(k+2),B(k+2)->cur bufs [last read of
//         those regions = X(k) pre-BAR -> 1-barrier separation] |
//         MFMA(aY,breg,mh1) | BAR
// MFMA clusters start with operands already in registers (except breg's one
// ~150cy lgkm at X). Never vmcnt(0) on just-issued loads; never drains in Y.
// MX-fp8 16x16x128, unit E8M0 scales = exact e4m3 math. LDS column-chunk
// layout (slot = col16*256 + row), conflict-free (verified 0 since R3).

typedef __attribute__((ext_vector_type(4))) float f32x4;
typedef __attribute__((ext_vector_type(2))) int i32x2;
typedef __attribute__((ext_vector_type(4))) int i32x4;
typedef __attribute__((ext_vector_type(8))) int i32x8;

#define FP8_MAX 448.0f
#define UNIT_SCALE 0x7F7F7F7F  // E8M0 127 = 2^0 in every byte

// ---------------- quantization pass: f32 -> e4m3fn bytes ----------------
__global__ void quant_fp8_kernel(const float* __restrict__ x,
                                 uint32_t* __restrict__ q,
                                 float mul, int n8) {
    int i = blockIdx.x * blockDim.x + threadIdx.x;
    if (i >= n8) return;
    const float4* xv = (const float4*)x;
    float4 v0 = xv[2 * i];
    float4 v1 = xv[2 * i + 1];
    float a[8] = {v0.x, v0.y, v0.z, v0.w, v1.x, v1.y, v1.z, v1.w};
#pragma unroll
    for (int j = 0; j < 8; ++j) {
        float t = a[j] * mul;
        t = fminf(fmaxf(t, -FP8_MAX), FP8_MAX);
        a[j] = t;
    }
    int lo = 0, hi = 0;
    lo = __builtin_amdgcn_cvt_pk_fp8_f32(a[0], a[1], lo, false);
    lo = __builtin_amdgcn_cvt_pk_fp8_f32(a[2], a[3], lo, true);
    hi = __builtin_amdgcn_cvt_pk_fp8_f32(a[4], a[5], hi, false);
    hi = __builtin_amdgcn_cvt_pk_fp8_f32(a[6], a[7], hi, true);
    i32x2 out;
    out.x = lo;
    out.y = hi;
    ((i32x2*)q)[i] = out;
}

// ---------------- MX-fp8 GEMM: C = 4*(A_q @ W_q^T) + bias ----------------
#define KTILES 32  // K / 128

__device__ static inline void gload_lds16(const void* g, void* l) {
    __builtin_amdgcn_global_load_lds(
        (const __attribute__((address_space(1))) void*)g,
        (__attribute__((address_space(3))) void*)l, 16, 0, 0);
}

// stage a full 32 KB operand K-tile: 4 calls x (512 thr x 16B)
#define STAGE_OP(GSRC, KB, LBASE)                                          \
    gload_lds16((GSRC) + (KB),      (LBASE) + t * 16);                     \
    gload_lds16((GSRC) + (KB) + 32, (LBASE) + 8192  + t * 16);             \
    gload_lds16((GSRC) + (KB) + 64, (LBASE) + 16384 + t * 16);             \
    gload_lds16((GSRC) + (KB) + 96, (LBASE) + 24576 + t * 16);

#define READ_A(LBASE, MH, DST)                                             \
    _Pragma("unroll") for (int m = 0; m < 4; ++m) {                        \
        i32x4 lo = *(const i32x4*)((LBASE) + aoff + (MH) * 1024 + m * 256);       \
        i32x4 hi = *(const i32x4*)((LBASE) + aoff + (MH) * 1024 + m * 256 + 4096);\
        DST[m] = (i32x8){lo[0], lo[1], lo[2], lo[3], hi[0], hi[1], hi[2], hi[3]}; \
    }

#define READ_B(LBASE, DST)                                                 \
    _Pragma("unroll") for (int n = 0; n < 4; ++n) {                        \
        i32x4 lo = *(const i32x4*)((LBASE) + boff + n * 256);                     \
        i32x4 hi = *(const i32x4*)((LBASE) + boff + n * 256 + 4096);              \
        DST[n] = (i32x8){lo[0], lo[1], lo[2], lo[3], hi[0], hi[1], hi[2], hi[3]}; \
    }

#define MFMA16(AR, BR, MH)                                                 \
    __builtin_amdgcn_s_setprio(1);                                         \
    _Pragma("unroll") for (int m = 0; m < 4; ++m)                          \
        _Pragma("unroll") for (int n = 0; n < 4; ++n)                      \
            acc[(MH) * 4 + m][n] =                                         \
                __builtin_amdgcn_mfma_scale_f32_16x16x128_f8f6f4(          \
                    AR[m], BR[n], acc[(MH) * 4 + m][n],                    \
                    0, 0, 0, UNIT_SCALE, 0, UNIT_SCALE);                   \
    __builtin_amdgcn_s_setprio(0);

#define BAR() __builtin_amdgcn_s_barrier()
#define VMW(N) asm volatile("s_waitcnt vmcnt(" #N ")" ::: "memory")

__global__ __launch_bounds__(512)
__attribute__((amdgpu_waves_per_eu(2, 2)))
void fp8_gemm_bias_kernel(
        const uint8_t* __restrict__ Aq, const uint8_t* __restrict__ Wq,
        const float* __restrict__ bias, float* __restrict__ C,
        int M, int N, int K) {
    // layout: [A0 | B0 | A1 | B1], each 32 KiB; computed offsets only.
    __shared__ __align__(16) uint8_t lds[131072];
    uint8_t* const LA0 = lds;
    uint8_t* const LB0 = lds + 32768;
    uint8_t* const LA1 = lds + 65536;
    uint8_t* const LB1 = lds + 98304;

    const int t = threadIdx.x;
    const int lane = t & 63;
    const int w = t >> 6;       // wave 0..7
    const int wr = w >> 2;      // wave row 0..1  (128 rows each)
    const int wc = w & 3;       // wave col 0..3  (64 cols each)
    const int lr = lane & 15;
    const int lk = lane >> 4;   // K-group (32 bytes)

    // XCD-aware swizzle: 256 blocks, 8 XCDs, 32 per XCD
    const int bid = blockIdx.x;
    const int swz = (bid & 7) * 32 + (bid >> 3);
    const int bm = swz >> 4;
    const int bn = swz & 15;

    const uint8_t* Abase = Aq + (size_t)(bm * 256) * K;
    const uint8_t* Bbase = Wq + (size_t)(bn * 256) * K;

    // staging source: call c: row = t&255, col16 = 2c + (t>>8)
    const int srow = t & 255;
    const int scol = (t >> 8) * 16;
    const uint8_t* gA = Abase + (size_t)srow * K + scol;
    const uint8_t* gB = Bbase + (size_t)srow * K + scol;

    // fragment read bases: A row = wr*128 + mh*64 + m*16 + lr, cols (2lk,2lk+1)
    const int aoff = lk * 8192 + wr * 2048 + lr * 16;
    const int boff = lk * 8192 + wc * 1024 + lr * 16;

    f32x4 acc[8][4];
#pragma unroll
    for (int mi = 0; mi < 8; ++mi)
#pragma unroll
        for (int ni = 0; ni < 4; ++ni)
            acc[mi][ni] = (f32x4){0.f, 0.f, 0.f, 0.f};

    i32x8 aX[4], aY[4], breg[4];

    // ---- prologue: A(0),B(0)->buf0, drain+bar; preload aX; stage tile 1 ----
    STAGE_OP(gA, 0, LA0)
    STAGE_OP(gB, 0, LB0)
    VMW(0);
    BAR();
    READ_A(LA0, 0, aX)               // A(0) mh0 -> aX
    STAGE_OP(gA, 128, LA1)           // A(1) — in flight across X(0)
    STAGE_OP(gB, 128, LB1)           // B(1)
    // entering X(0): 8 outstanding {A(1),B(1)} = steady state

    for (int k = 0; k < KTILES; ++k) {
        const int co = (k & 1) << 16;       // current buffer byte offset
        uint8_t* const LAc = lds + co;
        uint8_t* const LBc = lds + 32768 + co;
        uint8_t* const LAn = lds + (co ^ 65536);
        const int kbN = ((k + 2) & 31) * 128;  // tile k+2 (wraps at tail)

        // ---- X(k): B(k)+A_mh1(k) reads; MFMA off preloaded aX; drain; bar ----
        READ_B(LBc, breg)
        READ_A(LAc, 1, aY)
        MFMA16(aX, breg, 0)
        VMW(0);   // drains A(k+1),B(k+1) (issued at Y(k-1), ~1.5 phases aged)
        BAR();

        // ---- Y(k): preload next aX; stage tile k+2; MFMA off aY ----
        READ_A(LAn, 0, aX)           // A(k+1) mh0 (buffer visible since BAR)
        STAGE_OP(gA, kbN, LAc)       // last read of LAc: X(k) pre-BAR (1-bar sep)
        STAGE_OP(gB, kbN, LBc)       // last read of LBc: X(k) pre-BAR
        MFMA16(aY, breg, 1)
        BAR();
    }

    VMW(0);  // drain wrap-tail stages before epilogue

    // ---- epilogue: C/D layout col=lane&15, row=(lane>>4)*4+j ----
    const int crow0 = bm * 256 + wr * 128 + lk * 4;
    const int ccol0 = bn * 256 + wc * 64 + lr;
#pragma unroll
    for (int ni = 0; ni < 4; ++ni) {
        const int col = ccol0 + ni * 16;
        const float bv = bias[col];
#pragma unroll
        for (int mi = 0; mi < 8; ++mi) {
            const int row = crow0 + mi * 16;
#pragma unroll
            for (int j = 0; j < 4; ++j) {
                C[(size_t)(row + j) * N + col] = acc[mi][ni][j] * 4.0f + bv;
            }
        }
    }
}

extern "C" void kernel_launch(void* const* d_in, const int* in_sizes, int n_in,
                              void* d_out, int out_size, void* d_ws, size_t ws_size,
                              hipStream_t stream) {
    const int M = 4096, N = 4096, K = 4096;
    const float* input  = (const float*)d_in[0];   // [M][K] f32
    const float* weight = (const float*)d_in[1];   // [N][K] f32 (e4m3-grid values)
    const float* bias   = (const float*)d_in[2];   // [N] f32
    float* out = (float*)d_out;                    // [M][N] f32

    uint8_t* Aq = (uint8_t*)d_ws;                        // 16 MiB
    uint8_t* Wq = (uint8_t*)d_ws + (size_t)M * K;        // 16 MiB

    {
        int n8 = (M * K) / 8;
        int blocks = (n8 + 255) / 256;
        quant_fp8_kernel<<<blocks, 256, 0, stream>>>(input, (uint32_t*)Aq, 0.5f, n8);
        quant_fp8_kernel<<<blocks, 256, 0, stream>>>(weight, (uint32_t*)Wq, 1.0f, n8);
    }

    dim3 grid(256);  // (M/256) x (N/256), XCD-swizzled in-kernel
    fp8_gemm_bias_kernel<<<grid, 512, 0, stream>>>(Aq, Wq, bias, out, M, N, K);
}